// Round 1
// baseline (232.654 us; speedup 1.0000x reference)
//
#include <hip/hip_runtime.h>
#include <hip/hip_fp8.h>

// Problem geometry (fixed by the reference):
//   B=4, H=32, S=8192, D=128
//   cur   : [B,H,1,D] f32      (d_in[0], 16384 elems)
//   cache : [B,H,S,D] f32      (d_in[1], 134217728 elems) — fp8-representable values
//   s_in  : [1] f32            (d_in[2])
//   s_out : [1] f32            (d_in[3])
//   idx   : [1] i32            (d_in[4])
// out = (cache with row pos=clip(idx-1,0,S-1) replaced by fp8(cur/s_in)) * s_out
// Output f32, same shape as cache.

#define S_LEN 8192
#define D_LEN 128
// float4 elements per (b,h,s) row: D/4 = 32
#define F4_PER_ROW 32
#define ROW_SHIFT 5          // log2(32)
#define S_SHIFT 13           // log2(8192)

__device__ __forceinline__ float fp8_qdq(float x) {
    // f32 -> e4m3fn (RNE) -> f32
    __hip_fp8_e4m3 q(x);
    return (float)q;
}

__global__ __launch_bounds__(256) void PatchedKVCache_kernel(
    const float* __restrict__ cur,
    const float* __restrict__ cache,
    const float* __restrict__ s_in,
    const float* __restrict__ s_out,
    const int* __restrict__ idx,
    float* __restrict__ out,
    long long n4)
{
    const float so = s_out[0];
    int pos = idx[0] - 1;
    pos = pos < 0 ? 0 : (pos > S_LEN - 1 ? S_LEN - 1 : pos);

    const float4* __restrict__ cache4 = (const float4*)cache;
    float4* __restrict__ out4 = (float4*)out;

    long long i = (long long)blockIdx.x * blockDim.x + threadIdx.x;
    const long long stride = (long long)gridDim.x * blockDim.x;

    for (; i < n4; i += stride) {
        float4 v = cache4[i];
        const long long row = i >> ROW_SHIFT;          // (b*H+h)*S + s
        const int s = (int)(row & (S_LEN - 1));
        if (s == pos) {
            // Patched row: replace with quant-dequant of cur
            const long long bh = row >> S_SHIFT;       // b*H + h
            const int d0 = ((int)i & (F4_PER_ROW - 1)) * 4;
            const float* __restrict__ c = cur + bh * D_LEN + d0;
            const float si = s_in[0];
            v.x = fp8_qdq(c[0] / si);
            v.y = fp8_qdq(c[1] / si);
            v.z = fp8_qdq(c[2] / si);
            v.w = fp8_qdq(c[3] / si);
        }
        v.x *= so; v.y *= so; v.z *= so; v.w *= so;
        out4[i] = v;
    }
}

extern "C" void kernel_launch(void* const* d_in, const int* in_sizes, int n_in,
                              void* d_out, int out_size, void* d_ws, size_t ws_size,
                              hipStream_t stream)
{
    const float* cur   = (const float*)d_in[0];
    const float* cache = (const float*)d_in[1];
    const float* s_in  = (const float*)d_in[2];
    const float* s_out = (const float*)d_in[3];
    const int*   idx   = (const int*)d_in[4];
    float* out = (float*)d_out;

    const long long n4 = (long long)out_size / 4;   // 33,554,432 float4s

    const int threads = 256;
    const int blocks = 2048;                        // 256 CU * 8 blocks, grid-stride
    PatchedKVCache_kernel<<<blocks, threads, 0, stream>>>(
        cur, cache, s_in, s_out, idx, out, n4);
}